// Round 7
// baseline (129.508 us; speedup 1.0000x reference)
//
#include <hip/hip_runtime.h>

#define S_TOK 8192
#define NB 8
#define HQ 32
#define HKV 8
#define DH 128
#define KK 128
#define DIM 4096
#define NCOL4 (DIM / 4)   // 1024

// ---------------- GEMV core: 2 rows per block, 256 threads ----------------
// Column order per thread (c = t, t+256, t+512, t+768) and reduction order
// (shfl over 64 lanes, then 4-wave LDS combine) identical to R6 (passing).
__device__ __forceinline__ void gemv2(const float* __restrict__ W,
                                      const float* __restrict__ x,
                                      float* __restrict__ y,
                                      int r0, int t, float* red /* [4][16] */) {
    const int r1 = r0 + 1;
    const float4* w0p = (const float4*)(W + (size_t)r0 * DIM);
    const float4* w1p = (const float4*)(W + (size_t)r1 * DIM);
    const float4* x4 = (const float4*)x;
    float acc0[NB], acc1[NB];
#pragma unroll
    for (int b = 0; b < NB; ++b) { acc0[b] = 0.f; acc1[b] = 0.f; }
#pragma unroll 2
    for (int it = 0; it < 4; ++it) {
        const int c = t + it * 256;
        float4 w0 = w0p[c];
        float4 w1 = w1p[c];
#pragma unroll
        for (int b = 0; b < NB; ++b) {
            float4 xv = x4[(size_t)b * NCOL4 + c];
            acc0[b] += w0.x * xv.x + w0.y * xv.y + w0.z * xv.z + w0.w * xv.w;
            acc1[b] += w1.x * xv.x + w1.y * xv.y + w1.z * xv.z + w1.w * xv.w;
        }
    }
    const int lane = t & 63, wv = t >> 6;
#pragma unroll
    for (int b = 0; b < NB; ++b) {
#pragma unroll
        for (int o = 32; o > 0; o >>= 1) {
            acc0[b] += __shfl_down(acc0[b], o);
            acc1[b] += __shfl_down(acc1[b], o);
        }
    }
    if (lane == 0) {
#pragma unroll
        for (int b = 0; b < NB; ++b) {
            red[wv * 16 + b] = acc0[b];
            red[wv * 16 + 8 + b] = acc1[b];
        }
    }
    __syncthreads();
    if (t < 16) {
        float s = red[0 * 16 + t] + red[1 * 16 + t] + red[2 * 16 + t] + red[3 * 16 + t];
        int b = t & 7;
        int row = (t >> 3) ? r1 : r0;
        y[(size_t)b * DIM + row] = s;
    }
}

// ---------------- Kernel 1: fused { importance (blk 0..255) | topk (blk 256..263) |
//                                    Wq GEMV 2-row (blk 264..2311) } ----------------
// LDS kept < 5 KB so ALL blocks run at 8 blocks/CU (32 waves) — the R6 version's
// 35 KB LDS capped GEMV occupancy at 4 blocks/CU. Topk reads impbits from global
// (L2-resident, 32 KB/batch); its latency hides under the co-resident GEMV.
// Importance blocks are dispatched FIRST so the topk spin can never precede them.
__global__ __launch_bounds__(256) void fused_kernel(const float* __restrict__ attn_w,
                                                    const float* __restrict__ Wq,
                                                    const float* __restrict__ hidden,
                                                    unsigned* __restrict__ impbits,
                                                    int* __restrict__ topk,
                                                    float* __restrict__ q,
                                                    unsigned* __restrict__ impdone) {
    __shared__ __align__(16) int hist[256];        // 1 KB
    __shared__ unsigned sprefix;
    __shared__ int skrem;
    __shared__ int nsel, ntie;
    __shared__ unsigned selb[KK];                  // 512 B
    __shared__ int seli[KK];                       // 512 B
    __shared__ int tie[512];                       // 2 KB
    __shared__ float redg[4 * 16];                 // 256 B (gemv path)

    const int t = threadIdx.x;
    const int bl = blockIdx.x;

    if (bl >= 256 + NB) {
        // ---------- Wq GEMV path ----------
        gemv2(Wq, hidden, q, (bl - 256 - NB) * 2, t, redg);
        return;
    }

    if (bl < 256) {
        // ---------- importance path: serial h=0..31 sum (bit-exact vs R1/R6) ----------
        const int tok = bl * 256 + t;              // covers NB*S_TOK = 65536
        const int b = tok >> 13;                   // /8192
        const int s = tok & (S_TOK - 1);
        const float* p = attn_w + (size_t)b * HQ * S_TOK + s;
        float acc = 0.f;
#pragma unroll
        for (int h = 0; h < HQ; ++h) acc += p[(size_t)h * S_TOK];
        unsigned uu = __float_as_uint(acc * (1.0f / 32.0f));
        uu = (uu & 0x80000000u) ? ~uu : (uu | 0x80000000u);   // monotone map
        impbits[tok] = uu;
        __threadfence();
        __syncthreads();
        if (t == 0)
            __hip_atomic_fetch_add(impdone, 1u, __ATOMIC_ACQ_REL, __HIP_MEMORY_SCOPE_AGENT);
        return;
    }

    // ---------- topk path (b = bl - 256): wait for all importance blocks ----------
    if (t == 0) {
        while (__hip_atomic_load(impdone, __ATOMIC_ACQUIRE, __HIP_MEMORY_SCOPE_AGENT) < 256u)
            __builtin_amdgcn_s_sleep(2);
    }
    __syncthreads();
    __threadfence();

    const int b = bl - 256;
    const unsigned* ip = impbits + (size_t)b * S_TOK;
    if (t == 0) { sprefix = 0u; skrem = KK; nsel = 0; ntie = 0; }
    __syncthreads();

    // radix-256 select over global-resident mapped bits: find pattern T of 128th largest
    for (int shift = 24; shift >= 0; shift -= 8) {
        hist[t] = 0;
        __syncthreads();
        const unsigned pfx = sprefix;
        const int krem = skrem;
        if (shift == 24) {
            // values cluster into few exponent bins -> ballot-aggregate
            for (int i = t; i < S_TOK; i += 256) {
                int bin = ip[i] >> 24;
                unsigned long long rem = __ballot(1);
                while (rem) {
                    int fl = (int)__builtin_ctzll(rem);
                    int fbin = __shfl(bin, fl);
                    unsigned long long match = __ballot(bin == fbin);
                    if ((t & 63) == fl) atomicAdd(&hist[fbin], (int)__popcll(match));
                    rem &= ~match;
                }
            }
        } else {
            const unsigned pmask = 0xFFFFFFFFu << (shift + 8);
            for (int i = t; i < S_TOK; i += 256) {
                unsigned u = ip[i];
                if ((u & pmask) == pfx) atomicAdd(&hist[(u >> shift) & 255], 1);
            }
        }
        __syncthreads();
        // wave 0: parallel descending-bin scan
        if (t < 64) {
            int4 h4 = *(const int4*)&hist[252 - 4 * t];
            int h0 = h4.w, h1 = h4.z, h2 = h4.y, h3 = h4.x;   // descending-bin order
            int c0 = h0, c1 = c0 + h1, c2 = c1 + h2, c3 = c2 + h3;
            int inc = c3;
#pragma unroll
            for (int o = 1; o < 64; o <<= 1) {
                int yv = __shfl_up(inc, o);
                if (t >= o) inc += yv;
            }
            int excl = inc - c3;
            int cand = -1, before = 0;
            if      (excl + c0 >= krem) { cand = 0; before = excl; }
            else if (excl + c1 >= krem) { cand = 1; before = excl + c0; }
            else if (excl + c2 >= krem) { cand = 2; before = excl + c1; }
            else if (excl + c3 >= krem) { cand = 3; before = excl + c2; }
            unsigned long long ball = __ballot(cand >= 0);
            int win = (int)__builtin_ctzll(ball);
            if (t == win) {
                int p = 4 * t + cand;
                sprefix = pfx | ((unsigned)(255 - p) << shift);
                skrem = krem - before;
            }
        }
        __syncthreads();
    }
    const unsigned T = sprefix;

    // single sweep: collect strictly-greater (unordered) and ties (unordered, cap 512)
    for (int i = t; i < S_TOK; i += 256) {
        unsigned u = ip[i];
        if (u > T) {
            int p = atomicAdd(&nsel, 1);
            selb[p] = u; seli[p] = i;
        } else if (u == T) {
            int p = atomicAdd(&ntie, 1);
            if (p < 512) tie[p] = i;
        }
    }
    __syncthreads();
    const int g = nsel;
    const int tc = (ntie < 512) ? ntie : 512;
    for (int i = t; i < 512; i += 256) if (i >= tc) tie[i] = 0x7FFFFFFF;
    __syncthreads();

    // bitonic sort ties ascending by index (R0-verified)
    for (int ksz = 2; ksz <= 512; ksz <<= 1) {
        for (int j = ksz >> 1; j > 0; j >>= 1) {
            for (int i = t; i < 512; i += 256) {
                int l = i ^ j;
                if (l > i) {
                    bool up = ((i & ksz) == 0);
                    int a = tie[i], c = tie[l];
                    if ((a > c) == up) { tie[i] = c; tie[l] = a; }
                }
            }
            __syncthreads();
        }
    }
    const int r = KK - g;          // >= 1 by construction
    if (t < r) { selb[g + t] = T; seli[g + t] = tie[t]; }
    __syncthreads();

    // bitonic sort 128 selected: value descending, index ascending
    for (int ksz = 2; ksz <= KK; ksz <<= 1) {
        for (int j = ksz >> 1; j > 0; j >>= 1) {
            if (t < KK) {
                int i = t, l = i ^ j;
                if (l > i) {
                    bool up = ((i & ksz) == 0);
                    unsigned ab = selb[i], cb = selb[l];
                    int ai = seli[i], ci = seli[l];
                    bool aFirst = (ab > cb) || (ab == cb && ai < ci);
                    if (up ? !aFirst : aFirst) {
                        selb[i] = cb; selb[l] = ab;
                        seli[i] = ci; seli[l] = ai;
                    }
                }
            }
            __syncthreads();
        }
    }
    if (t < KK) topk[b * KK + t] = seli[t];
}

// ---------------- Kernel 2: pruned attention, 512 threads per (b,h) ----------------
__global__ __launch_bounds__(512) void attn_kernel(const float* __restrict__ q,
                                                   const float* __restrict__ k,
                                                   const float* __restrict__ v,
                                                   const int* __restrict__ topk,
                                                   float* __restrict__ ctx,
                                                   float* __restrict__ probs_out) {
    const int bh = blockIdx.x;
    const int b = bh >> 5, h = bh & 31, kvh = h >> 2;
    const int t = threadIdx.x;   // 512 threads

    __shared__ float qs[DH];
    __shared__ float scs[KK];
    __shared__ float ps[KK];
    __shared__ int idxs[KK];
    __shared__ float red2[2];
    __shared__ float red3[2];
    __shared__ float part[3][DH];

    if (t < DH) qs[t] = q[(size_t)(b * HQ + h) * DH + t] * 0.088388347648318447f; // 1/sqrt(128)
    if (t < KK) idxs[t] = topk[b * KK + t];
    __syncthreads();

    // scores: 4 threads per token, 32-dim quarter dots
    {
        const int tok = t >> 2, qpart = t & 3;
        const float4* k4 = (const float4*)(k +
            ((size_t)(b * HKV + kvh) * S_TOK + idxs[tok]) * DH + qpart * 32);
        float sc = 0.f;
#pragma unroll
        for (int d4 = 0; d4 < 8; ++d4) {
            float4 kv = k4[d4];
            int d0 = qpart * 32 + d4 * 4;
            sc += qs[d0] * kv.x + qs[d0 + 1] * kv.y + qs[d0 + 2] * kv.z + qs[d0 + 3] * kv.w;
        }
        sc += __shfl_xor(sc, 1);
        sc += __shfl_xor(sc, 2);
        if (qpart == 0) scs[tok] = sc;
    }
    __syncthreads();

    // softmax over 128 tokens (threads 0..127 hold one token each)
    float sc = (t < KK) ? scs[t] : -3.4e38f;
    if (t < KK) {
        float m = sc;
        for (int o = 32; o > 0; o >>= 1) m = fmaxf(m, __shfl_down(m, o));
        if ((t & 63) == 0) red2[t >> 6] = m;
    }
    __syncthreads();
    const float mx = fmaxf(red2[0], red2[1]);
    float p = 0.f;
    if (t < KK) {
        p = expf(sc - mx);
        float sm = p;
        for (int o = 32; o > 0; o >>= 1) sm += __shfl_down(sm, o);
        if ((t & 63) == 0) red3[t >> 6] = sm;
    }
    __syncthreads();
    if (t < KK) {
        p /= (red3[0] + red3[1]);
        ps[t] = p;
        probs_out[(size_t)(b * HQ + h) * KK + t] = p;
    }
    __syncthreads();

    // PV: 4 groups x 128 dims, 32 tokens per group, LDS combine
    {
        const int d = t & (DH - 1), grp = t >> 7;
        const float* vbase = v + (size_t)(b * HKV + kvh) * S_TOK * DH;
        float acc = 0.f;
        const int s0 = grp * 32;
#pragma unroll 4
        for (int s2 = s0; s2 < s0 + 32; ++s2) {
            acc += ps[s2] * vbase[(size_t)idxs[s2] * DH + d];
        }
        if (grp) part[grp - 1][d] = acc;
        __syncthreads();
        if (grp == 0)
            ctx[(size_t)(b * HQ + h) * DH + d] = acc + part[0][d] + part[1][d] + part[2][d];
    }
}

// ---------------- Kernel 3: Wo GEMV, 2 rows per block ----------------
__global__ __launch_bounds__(256) void gemv_wo_kernel(const float* __restrict__ Wo,
                                                      const float* __restrict__ ctx,
                                                      float* __restrict__ out) {
    __shared__ float redg[4 * 16];
    gemv2(Wo, ctx, out, blockIdx.x * 2, threadIdx.x, redg);
}

// ---------------- launcher ----------------
extern "C" void kernel_launch(void* const* d_in, const int* in_sizes, int n_in,
                              void* d_out, int out_size, void* d_ws, size_t ws_size,
                              hipStream_t stream) {
    const float* hidden = (const float*)d_in[0];   // [8,1,4096]
    const float* attn_w = (const float*)d_in[1];   // [8,32,1,8192]
    const float* k      = (const float*)d_in[2];   // [8,8,8192,128]
    const float* v      = (const float*)d_in[3];   // [8,8,8192,128]
    const float* Wq     = (const float*)d_in[4];   // [4096,4096]
    const float* Wo     = (const float*)d_in[5];   // [4096,4096]

    float* out   = (float*)d_out;                  // [8,4096]
    float* probs = out + NB * DIM;                 // [8,32,1,128]

    char* ws = (char*)d_ws;
    unsigned* impbits = (unsigned*)ws;              // 8*8192*4 = 262144 B
    int*   topkb = (int*)(ws + 262144);             // 8*128*4  =   4096 B
    float* q     = (float*)(ws + 266240);           // 8*4096*4 = 131072 B
    float* ctx   = (float*)(ws + 397312);           // 8*4096*4 = 131072 B
    unsigned* impdone = (unsigned*)(ws + 528384);   // arrival counter

    hipMemsetAsync(impdone, 0, 64, stream);         // counter starts at 0 each launch

    // blocks 0..255: importance; 256..263: topk (spin); 264..2311: Wq GEMV (2 rows)
    fused_kernel<<<256 + NB + DIM / 2, 256, 0, stream>>>(attn_w, Wq, hidden,
                                                         impbits, topkb, q, impdone);
    attn_kernel<<<NB * HQ, 512, 0, stream>>>(q, k, v, topkb, ctx, probs);
    gemv_wo_kernel<<<DIM / 2, 256, 0, stream>>>(Wo, ctx, out);
}

// Round 8
// 75.069 us; speedup vs baseline: 1.7252x; 1.7252x over previous
//
#include <hip/hip_runtime.h>

#define S_TOK 8192
#define NB 8
#define HQ 32
#define HKV 8
#define DH 128
#define KK 128
#define DIM 4096
#define NCOL4 (DIM / 4)   // 1024

// ---------------- Kernel 1: importance = mean over heads (verbatim R1) ----------------
__global__ __launch_bounds__(256) void importance_kernel(const float* __restrict__ attn_w,
                                                         float* __restrict__ imp) {
    int i = blockIdx.x * 256 + threadIdx.x;     // over NB*S_TOK
    if (i >= NB * S_TOK) return;
    int b = i >> 13;            // /8192
    int s = i & (S_TOK - 1);
    const float* p = attn_w + (size_t)b * HQ * S_TOK + s;
    float acc = 0.f;
#pragma unroll
    for (int h = 0; h < HQ; ++h) acc += p[(size_t)h * S_TOK];
    imp[i] = acc * (1.0f / 32.0f);
}

// ---------------- GEMV core: 2 rows per block, 256 threads (verbatim R6/R7) ----------------
__device__ __forceinline__ void gemv2(const float* __restrict__ W,
                                      const float* __restrict__ x,
                                      float* __restrict__ y,
                                      int r0, int t, float* red /* [4][16] */) {
    const int r1 = r0 + 1;
    const float4* w0p = (const float4*)(W + (size_t)r0 * DIM);
    const float4* w1p = (const float4*)(W + (size_t)r1 * DIM);
    const float4* x4 = (const float4*)x;
    float acc0[NB], acc1[NB];
#pragma unroll
    for (int b = 0; b < NB; ++b) { acc0[b] = 0.f; acc1[b] = 0.f; }
#pragma unroll 2
    for (int it = 0; it < 4; ++it) {
        const int c = t + it * 256;
        float4 w0 = w0p[c];
        float4 w1 = w1p[c];
#pragma unroll
        for (int b = 0; b < NB; ++b) {
            float4 xv = x4[(size_t)b * NCOL4 + c];
            acc0[b] += w0.x * xv.x + w0.y * xv.y + w0.z * xv.z + w0.w * xv.w;
            acc1[b] += w1.x * xv.x + w1.y * xv.y + w1.z * xv.z + w1.w * xv.w;
        }
    }
    const int lane = t & 63, wv = t >> 6;
#pragma unroll
    for (int b = 0; b < NB; ++b) {
#pragma unroll
        for (int o = 32; o > 0; o >>= 1) {
            acc0[b] += __shfl_down(acc0[b], o);
            acc1[b] += __shfl_down(acc1[b], o);
        }
    }
    if (lane == 0) {
#pragma unroll
        for (int b = 0; b < NB; ++b) {
            red[wv * 16 + b] = acc0[b];
            red[wv * 16 + 8 + b] = acc1[b];
        }
    }
    __syncthreads();
    if (t < 16) {
        float s = red[0 * 16 + t] + red[1 * 16 + t] + red[2 * 16 + t] + red[3 * 16 + t];
        int b = t & 7;
        int row = (t >> 3) ? r1 : r0;
        y[(size_t)b * DIM + row] = s;
    }
}

// ---------------- Kernel 2: fused { topk (blocks 0..7) | Wq GEMV 2-row (blocks 8..2055) }
// topk path verbatim R1 (85.1 µs run): LDS-staged mapped bits, ballot-aggregated
// first radix pass, wave-parallel bin scan, ordered tie scan, bitonic-128.
__global__ __launch_bounds__(256) void topk_gemvq_kernel(const float* __restrict__ imp,
                                                         int* __restrict__ topk,
                                                         const float* __restrict__ Wq,
                                                         const float* __restrict__ hidden,
                                                         float* __restrict__ q) {
    __shared__ __align__(16) unsigned mb[S_TOK];   // 32 KB mapped bits
    __shared__ __align__(16) int hist[256];
    __shared__ unsigned sprefix;
    __shared__ int skrem;
    __shared__ int nsel;
    __shared__ unsigned selb[KK];
    __shared__ int seli[KK];
    __shared__ float redg[4 * 16];

    const int t = threadIdx.x;

    if (blockIdx.x >= NB) {
        gemv2(Wq, hidden, q, (blockIdx.x - NB) * 2, t, redg);
        return;
    }

    // ---------- top-k path ----------
    const int b = blockIdx.x;
    const float* ip = imp + (size_t)b * S_TOK;
    for (int i = t; i < S_TOK; i += 256) {
        unsigned u = __float_as_uint(ip[i]);
        // monotone map: order of mapped bits == order of float values
        u = (u & 0x80000000u) ? ~u : (u | 0x80000000u);
        mb[i] = u;
    }
    if (t == 0) { sprefix = 0u; skrem = KK; nsel = 0; }
    __syncthreads();

    // radix-256 select: find bit pattern T of the 128th largest value
    for (int shift = 24; shift >= 0; shift -= 8) {
        hist[t] = 0;
        __syncthreads();
        const unsigned pfx = sprefix;
        const int krem = skrem;
        if (shift == 24) {
            // pass 1: values cluster into ~2 exponent bins -> ballot-aggregate
            for (int i = t; i < S_TOK; i += 256) {
                int bin = mb[i] >> 24;
                unsigned long long rem = __ballot(1);
                while (rem) {
                    int fl = (int)__builtin_ctzll(rem);
                    int fbin = __shfl(bin, fl);
                    unsigned long long match = __ballot(bin == fbin);
                    if ((t & 63) == fl) atomicAdd(&hist[fbin], (int)__popcll(match));
                    rem &= ~match;
                }
            }
        } else {
            const unsigned pmask = 0xFFFFFFFFu << (shift + 8);
            for (int i = t; i < S_TOK; i += 256) {
                unsigned u = mb[i];
                if ((u & pmask) == pfx) atomicAdd(&hist[(u >> shift) & 255], 1);
            }
        }
        __syncthreads();
        // wave 0: parallel descending-bin scan (replaces serial t==0 scan).
        if (t < 64) {
            int4 h4 = *(const int4*)&hist[252 - 4 * t];          // bins 252-4t .. 255-4t
            int h0 = h4.w, h1 = h4.z, h2 = h4.y, h3 = h4.x;      // descending-bin order
            int c0 = h0, c1 = c0 + h1, c2 = c1 + h2, c3 = c2 + h3;
            int inc = c3;
#pragma unroll
            for (int o = 1; o < 64; o <<= 1) {
                int y = __shfl_up(inc, o);
                if (t >= o) inc += y;
            }
            int excl = inc - c3;                                  // count in strictly higher bins
            int cand = -1, before = 0;
            if      (excl + c0 >= krem) { cand = 0; before = excl; }
            else if (excl + c1 >= krem) { cand = 1; before = excl + c0; }
            else if (excl + c2 >= krem) { cand = 2; before = excl + c1; }
            else if (excl + c3 >= krem) { cand = 3; before = excl + c2; }
            unsigned long long ball = __ballot(cand >= 0);
            int win = (int)__builtin_ctzll(ball);                 // smallest p == largest bin
            if (t == win) {
                int p = 4 * t + cand;
                sprefix = pfx | ((unsigned)(255 - p) << shift);
                skrem = krem - before;
            }
        }
        __syncthreads();
    }
    const unsigned T = sprefix;

    // collect strictly-greater (unordered; sorted later)
    for (int i = t; i < S_TOK; i += 256) {
        unsigned u = mb[i];
        if (u > T) {
            int p = atomicAdd(&nsel, 1);
            selb[p] = u; seli[p] = i;
        }
    }
    __syncthreads();
    const int g = nsel;
    const int r = KK - g;          // >= 1 by construction

    // wave 0: ordered scan collects the r smallest-index ties (exact semantics)
    if (t < 64) {
        int found = 0;
        for (int base0 = 0; base0 < S_TOK && found < r; base0 += 64) {
            bool is_tie = (mb[base0 + t] == T);
            unsigned long long ball = __ballot(is_tie);
            int pos = (int)__popcll(ball & ((1ull << t) - 1ull));
            if (is_tie && found + pos < r) {
                selb[g + found + pos] = T;
                seli[g + found + pos] = base0 + t;
            }
            found += (int)__popcll(ball);
        }
    }
    __syncthreads();

    // bitonic sort 128 selected: value descending, index ascending
    for (int ksz = 2; ksz <= KK; ksz <<= 1) {
        for (int j = ksz >> 1; j > 0; j >>= 1) {
            if (t < KK) {
                int i = t, l = i ^ j;
                if (l > i) {
                    bool up = ((i & ksz) == 0);
                    unsigned ab = selb[i], cb = selb[l];
                    int ai = seli[i], ci = seli[l];
                    bool aFirst = (ab > cb) || (ab == cb && ai < ci);
                    if (up ? !aFirst : aFirst) {
                        selb[i] = cb; selb[l] = ab;
                        seli[i] = ci; seli[l] = ai;
                    }
                }
            }
            __syncthreads();
        }
    }
    if (t < KK) topk[b * KK + t] = seli[t];
}

// ---------------- Kernel 3: pruned attention, 512 threads per (b,h) (verbatim R7) ----------
__global__ __launch_bounds__(512) void attn_kernel(const float* __restrict__ q,
                                                   const float* __restrict__ k,
                                                   const float* __restrict__ v,
                                                   const int* __restrict__ topk,
                                                   float* __restrict__ ctx,
                                                   float* __restrict__ probs_out) {
    const int bh = blockIdx.x;
    const int b = bh >> 5, h = bh & 31, kvh = h >> 2;
    const int t = threadIdx.x;   // 512 threads

    __shared__ float qs[DH];
    __shared__ float scs[KK];
    __shared__ float ps[KK];
    __shared__ int idxs[KK];
    __shared__ float red2[2];
    __shared__ float red3[2];
    __shared__ float part[3][DH];

    if (t < DH) qs[t] = q[(size_t)(b * HQ + h) * DH + t] * 0.088388347648318447f; // 1/sqrt(128)
    if (t < KK) idxs[t] = topk[b * KK + t];
    __syncthreads();

    // scores: 4 threads per token, 32-dim quarter dots
    {
        const int tok = t >> 2, qpart = t & 3;
        const float4* k4 = (const float4*)(k +
            ((size_t)(b * HKV + kvh) * S_TOK + idxs[tok]) * DH + qpart * 32);
        float sc = 0.f;
#pragma unroll
        for (int d4 = 0; d4 < 8; ++d4) {
            float4 kv = k4[d4];
            int d0 = qpart * 32 + d4 * 4;
            sc += qs[d0] * kv.x + qs[d0 + 1] * kv.y + qs[d0 + 2] * kv.z + qs[d0 + 3] * kv.w;
        }
        sc += __shfl_xor(sc, 1);
        sc += __shfl_xor(sc, 2);
        if (qpart == 0) scs[tok] = sc;
    }
    __syncthreads();

    // softmax over 128 tokens (threads 0..127 hold one token each)
    float sc = (t < KK) ? scs[t] : -3.4e38f;
    if (t < KK) {
        float m = sc;
        for (int o = 32; o > 0; o >>= 1) m = fmaxf(m, __shfl_down(m, o));
        if ((t & 63) == 0) red2[t >> 6] = m;
    }
    __syncthreads();
    const float mx = fmaxf(red2[0], red2[1]);
    float p = 0.f;
    if (t < KK) {
        p = expf(sc - mx);
        float sm = p;
        for (int o = 32; o > 0; o >>= 1) sm += __shfl_down(sm, o);
        if ((t & 63) == 0) red3[t >> 6] = sm;
    }
    __syncthreads();
    if (t < KK) {
        p /= (red3[0] + red3[1]);
        ps[t] = p;
        probs_out[(size_t)(b * HQ + h) * KK + t] = p;
    }
    __syncthreads();

    // PV: 4 groups x 128 dims, 32 tokens per group, LDS combine
    {
        const int d = t & (DH - 1), grp = t >> 7;
        const float* vbase = v + (size_t)(b * HKV + kvh) * S_TOK * DH;
        float acc = 0.f;
        const int s0 = grp * 32;
#pragma unroll 4
        for (int s2 = s0; s2 < s0 + 32; ++s2) {
            acc += ps[s2] * vbase[(size_t)idxs[s2] * DH + d];
        }
        if (grp) part[grp - 1][d] = acc;
        __syncthreads();
        if (grp == 0)
            ctx[(size_t)(b * HQ + h) * DH + d] = acc + part[0][d] + part[1][d] + part[2][d];
    }
}

// ---------------- Kernel 4: Wo GEMV, 2 rows per block ----------------
__global__ __launch_bounds__(256) void gemv_wo_kernel(const float* __restrict__ Wo,
                                                      const float* __restrict__ ctx,
                                                      float* __restrict__ out) {
    __shared__ float redg[4 * 16];
    gemv2(Wo, ctx, out, blockIdx.x * 2, threadIdx.x, redg);
}

// ---------------- launcher (R1 structure: 4 launches, no spin, no memset) ----------------
extern "C" void kernel_launch(void* const* d_in, const int* in_sizes, int n_in,
                              void* d_out, int out_size, void* d_ws, size_t ws_size,
                              hipStream_t stream) {
    const float* hidden = (const float*)d_in[0];   // [8,1,4096]
    const float* attn_w = (const float*)d_in[1];   // [8,32,1,8192]
    const float* k      = (const float*)d_in[2];   // [8,8,8192,128]
    const float* v      = (const float*)d_in[3];   // [8,8,8192,128]
    const float* Wq     = (const float*)d_in[4];   // [4096,4096]
    const float* Wo     = (const float*)d_in[5];   // [4096,4096]

    float* out   = (float*)d_out;                  // [8,4096]
    float* probs = out + NB * DIM;                 // [8,32,1,128]

    char* ws = (char*)d_ws;
    float* imp   = (float*)ws;                      // 8*8192*4 = 262144 B
    int*   topkb = (int*)(ws + 262144);             // 8*128*4  =   4096 B
    float* q     = (float*)(ws + 266240);           // 8*4096*4 = 131072 B
    float* ctx   = (float*)(ws + 397312);           // 8*4096*4 = 131072 B

    importance_kernel<<<(NB * S_TOK) / 256, 256, 0, stream>>>(attn_w, imp);
    // fused: blocks 0..7 topk (reads imp from prior launch); 8..2055 Wq GEMV (2 rows)
    topk_gemvq_kernel<<<NB + DIM / 2, 256, 0, stream>>>(imp, topkb, Wq, hidden, q);
    attn_kernel<<<NB * HQ, 512, 0, stream>>>(q, k, v, topkb, ctx, probs);
    gemv_wo_kernel<<<DIM / 2, 256, 0, stream>>>(Wo, ctx, out);
}